// Round 4
// baseline (825.451 us; speedup 1.0000x reference)
//
#include <hip/hip_runtime.h>
#include <math.h>

// B=512, T=256, D=81, H=128
#define BB 512
#define TT 256
#define DD 81
#define HH 128

typedef _Float16 half8 __attribute__((ext_vector_type(8)));
typedef float    f32x4 __attribute__((ext_vector_type(4)));

// ---- d_ws blob geometry (float4 units) ----
#define BLOB_LDS_ELEMS 5632          // W1 chunks (4096) + W2 chunks (1536)
#define BLOB_W4_ELEMS  14336        // 28 frags x 512 threads
#define BLOB_W4_OFF    BLOB_LDS_ELEMS
#define WS_ELEMS       (BLOB_LDS_ELEMS + BLOB_W4_ELEMS)

// ---- LDS layout (bytes) ----
#define W1_OFF    0        // 64 chunks x 1 KB
#define W2_OFF    65536    // 24 chunks x 1 KB
#define HS_OFF    90112    // 2 rows x 544 B: [h(128);c(128)] fp16 + 16 pad halves
#define HS_STRIDE 544
#define ACT_OFF   91200    // 2 buffers x (2 rows x 448 B): [xw(81);h(128);1;pad] fp16
#define ACT_ROW   448
#define ACT_BUF   896
#define A1_OFF    92992    // 2 rows x 288 B: a1(128) fp16 + 16 pad halves
#define A1_STRIDE 288
#define LDS_BYTES 93568

__device__ __forceinline__ float fast_sig(float x)  { return 1.f / (1.f + __expf(-x)); }
__device__ __forceinline__ float fast_tanh(float x) { return 1.f - 2.f / (__expf(2.f * x) + 1.f); }

__device__ __forceinline__ float4 pack8h(const float* v) {
    union { float4 f4; _Float16 h[8]; } u;
#pragma unroll
    for (int c = 0; c < 8; ++c) u.h[c] = (_Float16)v[c];
    return u.f4;
}

// ---------------- repack kernels ----------------
// LDS image: B-fragment chunks, 1 KB each, lane l's 16 B at chunk + l*16.
// chunk(nt,kt), lane l: W[n][kb..kb+7] fp16, n = 16*nt + (l&15), kb = 32*kt + (l>>4)*8
__global__ void repack_lds_blob(const float* __restrict__ W1, const float* __restrict__ W2,
                                float4* __restrict__ dst) {
    int tid = blockIdx.x * blockDim.x + threadIdx.x;
    if (tid >= BLOB_LDS_ELEMS) return;
    float v[8];
    if (tid < 4096) {                      // W1 [128][256], chunk c = nt*8+kt
        int c = tid >> 6, l = tid & 63;
        int nt = c >> 3, kt = c & 7;
        int n = 16 * nt + (l & 15);
        int kb = 32 * kt + ((l >> 4) << 3);
#pragma unroll
        for (int c2 = 0; c2 < 8; ++c2) v[c2] = W1[(size_t)n * 256 + kb + c2];
    } else {                               // W2 [81][128], chunk c = nt*4+kt, pad n>=81
        int idx = tid - 4096;
        int c = idx >> 6, l = idx & 63;
        int nt = c >> 2, kt = c & 3;
        int n = 16 * nt + (l & 15);
        int kb = 32 * kt + ((l >> 4) << 3);
#pragma unroll
        for (int c2 = 0; c2 < 8; ++c2)
            v[c2] = (n < 81) ? W2[(size_t)n * 128 + kb + c2] : 0.f;
    }
    dst[tid] = pack8h(v);
}

// W4 register fragments. frag f = j*7 + kt, j = GATE index (i,f,g,o), thread r = w*64+l.
// Output q = 64w + 16j + (l&15)  ->  original gate row n = 128*j + 16*w + (l&15).
// Fused K (224): k<81 Wih[n][k]; 81<=k<209 Whh[n][k-81]; k==209 bih[n]+bhh[n]; else 0.
__global__ void repack_w4(const float* __restrict__ Wih, const float* __restrict__ Whh,
                          const float* __restrict__ bih, const float* __restrict__ bhh,
                          float4* __restrict__ dst) {
    int tid = blockIdx.x * blockDim.x + threadIdx.x;
    if (tid >= BLOB_W4_ELEMS) return;
    int f = tid >> 9, r = tid & 511;
    int w = r >> 6, l = r & 63;
    int j = f / 7, kt = f - 7 * j;
    int n = 128 * j + 16 * w + (l & 15);
    int kb = 32 * kt + ((l >> 4) << 3);
    float v[8];
#pragma unroll
    for (int c = 0; c < 8; ++c) {
        int k = kb + c;
        float x;
        if (k < 81)        x = Wih[(size_t)n * 81 + k];
        else if (k < 209)  x = Whh[(size_t)n * 128 + (k - 81)];
        else if (k == 209) x = bih[n] + bhh[n];
        else               x = 0.f;
        v[c] = x;
    }
    dst[tid] = pack8h(v);
}

// ---------------- main kernel: 256 blocks x 512 threads, 2 rows/block ----------------
// 3 barriers/step:  A(p1 + gate-kt3..6) | B'(waves0,1: e+softmax+xw) | D(gate-kt0..2 + LSTM)
__global__ __launch_bounds__(512, 2)
void encoder_kernel(const float* __restrict__ X,
                    const float* __restrict__ b1, const float* __restrict__ b2,
                    const float4* __restrict__ wlds, const float4* __restrict__ w4q,
                    float* __restrict__ out_h, float* __restrict__ out_alpha) {
    const int tid = threadIdx.x;
    const int w   = tid >> 6;
    const int l   = tid & 63;
    const int c16 = l & 15;
    const int b0  = blockIdx.x * 2;

    __shared__ __align__(16) unsigned char lds[LDS_BYTES];

    // stage W1/W2 fragment chunks into LDS (90112 B = 11 x 512 float4)
#pragma unroll
    for (int i = 0; i < 11; ++i)
        ((float4*)lds)[i * 512 + tid] = wlds[i * 512 + tid];

    // resident W4 B-fragments (112 regs)
    half8 wf[4][7];
#pragma unroll
    for (int j = 0; j < 4; ++j)
#pragma unroll
        for (int kt = 0; kt < 7; ++kt) {
            float4 t = w4q[(j * 7 + kt) * 512 + tid];
            wf[j][kt] = *(half8*)&t;
        }

    const float breg1 = b1[16 * w + c16];
    float b2q[6];
#pragma unroll
    for (int j = 0; j < 6; ++j) {
        int idx = 16 * j + c16;
        b2q[j] = (idx < DD) ? b2[idx] : 0.f;
    }

    // zero h/c/act/a1 state
    for (int i = tid; i < (LDS_BYTES - HS_OFF) / 4; i += 512)
        ((float*)(lds + HS_OFF))[i] = 0.f;
    __syncthreads();
    if (tid < 4) {   // const-1 slot (k=209) in both act buffers, both rows
        int buf = tid >> 1, r = tid & 1;
        ((_Float16*)(lds + ACT_OFF + buf * ACT_BUF + r * ACT_ROW))[209] = (_Float16)1.0f;
    }
    __syncthreads();

    float c0 = 0.f, c1 = 0.f;   // fp32 cell state, lane-resident (lanes l<16)
    const unsigned offA_hs  = (l & 1) * HS_STRIDE + (l >> 4) * 16;
    const unsigned offA_act = (l & 1) * ACT_ROW   + (l >> 4) * 16;
    const unsigned offA_a1  = (l & 1) * A1_STRIDE + (l >> 4) * 16;

#pragma unroll 1
    for (int t = 0; t < TT; ++t) {
        const unsigned rbuf = (unsigned)(t & 1) * ACT_BUF;
        const unsigned wbuf = (unsigned)((t + 1) & 1) * ACT_BUF;

        // x_t prefetch (waves 0,1 = rows 0,1); lane holds x[16j + c16]
        float xq[6] = {0.f, 0.f, 0.f, 0.f, 0.f, 0.f};
        if (w < 2) {
            const float* xr = X + ((size_t)(b0 + w) * TT + t) * DD;
#pragma unroll
            for (int j = 0; j < 5; ++j) xq[j] = xr[16 * j + c16];
            if (c16 == 0) xq[5] = xr[80];
        }

        // ---- stage A: p1 (wave w -> a1 ntile w) + gate kt3..6 (h part + bias)
        f32x4 g0 = {0,0,0,0}, g1 = {0,0,0,0}, g2 = {0,0,0,0}, g3 = {0,0,0,0};
        {
            f32x4 ae = {0,0,0,0}, ao = {0,0,0,0};
#pragma unroll
            for (int kt = 0; kt < 8; ++kt) {
                half8 a = *(const half8*)(lds + HS_OFF + offA_hs + kt * 64);
                half8 b = *(const half8*)(lds + W1_OFF + (w * 8 + kt) * 1024 + l * 16);
                if (kt & 1) ao = __builtin_amdgcn_mfma_f32_16x16x32_f16(a, b, ao, 0, 0, 0);
                else        ae = __builtin_amdgcn_mfma_f32_16x16x32_f16(a, b, ae, 0, 0, 0);
            }
#pragma unroll
            for (int kt = 3; kt < 7; ++kt) {
                half8 a = *(const half8*)(lds + ACT_OFF + rbuf + offA_act + kt * 64);
                g0 = __builtin_amdgcn_mfma_f32_16x16x32_f16(a, wf[0][kt], g0, 0, 0, 0);
                g1 = __builtin_amdgcn_mfma_f32_16x16x32_f16(a, wf[1][kt], g1, 0, 0, 0);
                g2 = __builtin_amdgcn_mfma_f32_16x16x32_f16(a, wf[2][kt], g2, 0, 0, 0);
                g3 = __builtin_amdgcn_mfma_f32_16x16x32_f16(a, wf[3][kt], g3, 0, 0, 0);
            }
            if (l < 16) {
                _Float16* a1f = (_Float16*)(lds + A1_OFF);
                a1f[16 * w + l]       = (_Float16)fast_tanh(ae[0] + ao[0] + breg1);
                a1f[144 + 16 * w + l] = (_Float16)fast_tanh(ae[1] + ao[1] + breg1);
            }
        }
        __syncthreads();

        // ---- stage B': waves 0,1 — full e (redundant both rows), in-wave softmax, xw
        if (w < 2) {
            f32x4 e0 = {0,0,0,0}, e1 = e0, e2v = e0, e3 = e0, e4 = e0, e5 = e0;
#pragma unroll
            for (int kt = 0; kt < 4; ++kt) {
                half8 a = *(const half8*)(lds + A1_OFF + offA_a1 + kt * 64);
                e0  = __builtin_amdgcn_mfma_f32_16x16x32_f16(a, *(const half8*)(lds + W2_OFF + (0 * 4 + kt) * 1024 + l * 16), e0, 0, 0, 0);
                e1  = __builtin_amdgcn_mfma_f32_16x16x32_f16(a, *(const half8*)(lds + W2_OFF + (1 * 4 + kt) * 1024 + l * 16), e1, 0, 0, 0);
                e2v = __builtin_amdgcn_mfma_f32_16x16x32_f16(a, *(const half8*)(lds + W2_OFF + (2 * 4 + kt) * 1024 + l * 16), e2v, 0, 0, 0);
                e3  = __builtin_amdgcn_mfma_f32_16x16x32_f16(a, *(const half8*)(lds + W2_OFF + (3 * 4 + kt) * 1024 + l * 16), e3, 0, 0, 0);
                e4  = __builtin_amdgcn_mfma_f32_16x16x32_f16(a, *(const half8*)(lds + W2_OFF + (4 * 4 + kt) * 1024 + l * 16), e4, 0, 0, 0);
                e5  = __builtin_amdgcn_mfma_f32_16x16x32_f16(a, *(const half8*)(lds + W2_OFF + (5 * 4 + kt) * 1024 + l * 16), e5, 0, 0, 0);
            }
            // row w lives in reg index w (lanes' rows replicate mod 2 -> all lanes consistent)
            float ev0 = e0[w] + b2q[0], ev1 = e1[w] + b2q[1], ev2 = e2v[w] + b2q[2];
            float ev3 = e3[w] + b2q[3], ev4 = e4[w] + b2q[4];
            float ev5 = (c16 == 0) ? (e5[w] + b2q[5]) : -INFINITY;
            float m = fmaxf(fmaxf(fmaxf(ev0, ev1), fmaxf(ev2, ev3)), fmaxf(ev4, ev5));
#pragma unroll
            for (int off = 1; off < 16; off <<= 1) m = fmaxf(m, __shfl_xor(m, off, 64));
            float p0 = __expf(ev0 - m), p1 = __expf(ev1 - m), p2 = __expf(ev2 - m);
            float p3 = __expf(ev3 - m), p4 = __expf(ev4 - m), p5 = __expf(ev5 - m);
            float s = p0 + p1 + p2 + p3 + p4 + p5;
#pragma unroll
            for (int off = 1; off < 16; off <<= 1) s += __shfl_xor(s, off, 64);
            float inv = 1.f / s;
            if (l < 16) {
                float* oa = out_alpha + ((size_t)(b0 + w) * TT + t) * DD;
                _Float16* act = (_Float16*)(lds + ACT_OFF + rbuf + w * ACT_ROW);
                float al;
                al = p0 * inv; oa[l]      = al; act[l]      = (_Float16)(al * xq[0]);
                al = p1 * inv; oa[l + 16] = al; act[l + 16] = (_Float16)(al * xq[1]);
                al = p2 * inv; oa[l + 32] = al; act[l + 32] = (_Float16)(al * xq[2]);
                al = p3 * inv; oa[l + 48] = al; act[l + 48] = (_Float16)(al * xq[3]);
                al = p4 * inv; oa[l + 64] = al; act[l + 64] = (_Float16)(al * xq[4]);
                if (l == 0) { al = p5 * inv; oa[80] = al; act[80] = (_Float16)(al * xq[5]); }
            }
        }
        __syncthreads();

        // ---- stage D: gate kt0..2 (xw part) + in-lane LSTM pointwise
#pragma unroll
        for (int kt = 0; kt < 3; ++kt) {
            half8 a = *(const half8*)(lds + ACT_OFF + rbuf + offA_act + kt * 64);
            g0 = __builtin_amdgcn_mfma_f32_16x16x32_f16(a, wf[0][kt], g0, 0, 0, 0);
            g1 = __builtin_amdgcn_mfma_f32_16x16x32_f16(a, wf[1][kt], g1, 0, 0, 0);
            g2 = __builtin_amdgcn_mfma_f32_16x16x32_f16(a, wf[2][kt], g2, 0, 0, 0);
            g3 = __builtin_amdgcn_mfma_f32_16x16x32_f16(a, wf[3][kt], g3, 0, 0, 0);
        }
        if (l < 16) {
            int u = 16 * w + l;
            // rows 0,1 in acc regs 0,1; g0=i, g1=f, g2=g, g3=o for u
            c0 = fast_sig(g1[0]) * c0 + fast_sig(g0[0]) * fast_tanh(g2[0]);
            float h0v = fast_sig(g3[0]) * fast_tanh(c0);
            c1 = fast_sig(g1[1]) * c1 + fast_sig(g0[1]) * fast_tanh(g2[1]);
            float h1v = fast_sig(g3[1]) * fast_tanh(c1);
            _Float16* hsb = (_Float16*)(lds + HS_OFF);
            hsb[u]             = (_Float16)h0v;  hsb[128 + u]       = (_Float16)c0;
            hsb[272 + u]       = (_Float16)h1v;  hsb[272 + 128 + u] = (_Float16)c1;
            _Float16* actw = (_Float16*)(lds + ACT_OFF + wbuf);
            actw[81 + u]       = (_Float16)h0v;
            actw[224 + 81 + u] = (_Float16)h1v;
            out_h[((size_t)b0 * TT + t) * HH + u]       = h0v;
            out_h[((size_t)(b0 + 1) * TT + t) * HH + u] = h1v;
        }
        __syncthreads();
    }
}

extern "C" void kernel_launch(void* const* d_in, const int* in_sizes, int n_in,
                              void* d_out, int out_size, void* d_ws, size_t ws_size,
                              hipStream_t stream) {
    const float* X   = (const float*)d_in[0];
    const float* W1  = (const float*)d_in[1];
    const float* b1  = (const float*)d_in[2];
    const float* W2  = (const float*)d_in[3];
    const float* b2  = (const float*)d_in[4];
    const float* Wih = (const float*)d_in[5];
    const float* Whh = (const float*)d_in[6];
    const float* bih = (const float*)d_in[7];
    const float* bhh = (const float*)d_in[8];

    if (ws_size < (size_t)WS_ELEMS * sizeof(float4)) return;  // ~320 KB scratch

    float4* blob = (float4*)d_ws;
    float4* wlds = blob;
    float4* w4q  = blob + BLOB_W4_OFF;

    repack_lds_blob<<<(BLOB_LDS_ELEMS + 255) / 256, 256, 0, stream>>>(W1, W2, wlds);
    repack_w4<<<(BLOB_W4_ELEMS + 255) / 256, 256, 0, stream>>>(Wih, Whh, bih, bhh, w4q);

    float* out_h     = (float*)d_out;                        // [512,256,128]
    float* out_alpha = (float*)d_out + (size_t)BB * TT * HH; // [512,256,81]

    encoder_kernel<<<BB / 2, 512, 0, stream>>>(X, b1, b2, wlds, w4q, out_h, out_alpha);
}